// Round 1
// baseline (645.193 us; speedup 1.0000x reference)
//
#include <hip/hip_runtime.h>
#include <stdint.h>

#define DEVI static __device__ __forceinline__

typedef __attribute__((ext_vector_type(8))) __bf16 bf16x8;
typedef __attribute__((ext_vector_type(4))) float f32x4;

#define MFMA16(a, b, c) __builtin_amdgcn_mfma_f32_16x16x32_bf16((a), (b), (c), 0, 0, 0)

DEVI uint16_t f2bf(float f) {
  uint32_t u = __builtin_bit_cast(uint32_t, f);
  u += 0x7fffu + ((u >> 16) & 1u);   // RNE (no NaN inputs here)
  return (uint16_t)(u >> 16);
}

DEVI void gload16(const void* g, void* l) {
  __builtin_amdgcn_global_load_lds((const __attribute__((address_space(1))) void*)g,
                                   (__attribute__((address_space(3))) void*)l, 16, 0, 0);
}

// ---------------- f32 -> bf16 convert (8 elems/thread) ----------------
__global__ __launch_bounds__(256) void cvt_bf16(const float* __restrict__ in,
                                                uint16_t* __restrict__ out, long n) {
  long i = ((long)blockIdx.x * 256 + threadIdx.x) * 8;
  if (i >= n) return;
  float4 a = *(const float4*)(in + i);
  float4 b = *(const float4*)(in + i + 4);
  union { uint16_t u[8]; uint4 v; } r;
  r.u[0] = f2bf(a.x); r.u[1] = f2bf(a.y); r.u[2] = f2bf(a.z); r.u[3] = f2bf(a.w);
  r.u[4] = f2bf(b.x); r.u[5] = f2bf(b.y); r.u[6] = f2bf(b.z); r.u[7] = f2bf(b.w);
  *(uint4*)(out + i) = r.v;
}

// ---------------- W f32 [1024][1024] -> Wt bf16 [n][k] (transposed) ----------------
__global__ __launch_bounds__(256) void wtrans(const float* __restrict__ W,
                                              uint16_t* __restrict__ Wt) {
  __shared__ float t[64][65];
  const int ti = blockIdx.y * 64, tj = blockIdx.x * 64;
  {
    int r = threadIdx.x >> 2, c0 = (threadIdx.x & 3) * 16;
#pragma unroll
    for (int i = 0; i < 16; i += 4) {
      float4 v = *(const float4*)(W + (size_t)(ti + r) * 1024 + tj + c0 + i);
      t[r][c0 + i + 0] = v.x; t[r][c0 + i + 1] = v.y;
      t[r][c0 + i + 2] = v.z; t[r][c0 + i + 3] = v.w;
    }
  }
  __syncthreads();
  {
    int c = threadIdx.x >> 2, r0 = (threadIdx.x & 3) * 16;
    union { uint16_t u[16]; uint4 v[2]; } b;
#pragma unroll
    for (int i = 0; i < 16; ++i) b.u[i] = f2bf(t[r0 + i][c]);
    uint16_t* dst = Wt + (size_t)(tj + c) * 1024 + ti + r0;
    *(uint4*)dst = b.v[0];
    *(uint4*)(dst + 8) = b.v[1];
  }
}

// ---------------- C[M][1024] = A[M][1024] @ Wt^T (+bias) ----------------
// A bf16 [M][1024]; Bt bf16 [1024][1024] = W^T ([n][k]); C f32 or bf16.
// m97 structure: 128x128 tile, BK=32, 4 waves, dbuf LDS via global_load_lds x16.
__global__ __launch_bounds__(256) void gemm_bt(const uint16_t* __restrict__ A,
                                               const uint16_t* __restrict__ Bt,
                                               const float* __restrict__ bias,
                                               void* __restrict__ C, int c_f32) {
  __shared__ uint16_t As[2][128 * 32];
  __shared__ uint16_t Bs[2][128 * 32];
  const int tid = threadIdx.x;
  const int lane = tid & 63;
  const int wv = tid >> 6, wr = wv >> 1, wc = wv & 1;
  const int lc = lane & 15, lq = lane >> 4;
  const size_t m0 = (size_t)blockIdx.y * 128;
  const int n0 = blockIdx.x * 128;

  f32x4 acc[4][4] = {};

  const uint8_t* Ab = (const uint8_t*)A + m0 * 2048;
  const uint8_t* Bb = (const uint8_t*)Bt + (size_t)n0 * 2048;
  const int o0 = tid * 16;

  auto stage = [&](int bsel, int kt) {
    const int k0b = kt * 64;
#pragma unroll
    for (int is = 0; is < 2; ++is) {
      int o = o0 + is * 4096;
      int row = o >> 6, kb = o & 63;
      gload16(Ab + (size_t)row * 2048 + k0b + kb, (uint16_t*)As[bsel] + (o >> 1));
      gload16(Bb + (size_t)row * 2048 + k0b + kb, (uint16_t*)Bs[bsel] + (o >> 1));
    }
  };

  stage(0, 0);
  int buf = 0;
  for (int kt = 0; kt < 32; ++kt) {
    __syncthreads();            // stage(kt) drained (vmcnt0) + prev reads done
    if (kt + 1 < 32) stage(buf ^ 1, kt + 1);
    const uint16_t* as = As[buf];
    const uint16_t* bs = Bs[buf];
    bf16x8 a[4], b[4];
#pragma unroll
    for (int i = 0; i < 4; ++i) {
      a[i] = *(const bf16x8*)(as + (wr * 64 + i * 16 + lc) * 32 + lq * 8);
      b[i] = *(const bf16x8*)(bs + (wc * 64 + i * 16 + lc) * 32 + lq * 8);
    }
#pragma unroll
    for (int mi = 0; mi < 4; ++mi)
#pragma unroll
      for (int ni = 0; ni < 4; ++ni)
        acc[mi][ni] = MFMA16(a[mi], b[ni], acc[mi][ni]);
    buf ^= 1;
  }

#pragma unroll
  for (int mi = 0; mi < 4; ++mi) {
#pragma unroll
    for (int ni = 0; ni < 4; ++ni) {
      const int col = n0 + wc * 64 + ni * 16 + lc;
      const float bb = bias[col];
#pragma unroll
      for (int r = 0; r < 4; ++r) {
        const size_t row = m0 + wr * 64 + mi * 16 + lq * 4 + r;
        float v = acc[mi][ni][r] + bb;
        if (c_f32) ((float*)C)[row * 1024 + col] = v;
        else       ((uint16_t*)C)[row * 1024 + col] = f2bf(v);
      }
    }
  }
}

// ---------------- block-diagonal attention ----------------
// one block per (b,h,g); 4 waves, each owns 32 q-rows.
__global__ __launch_bounds__(256) void attn(const uint16_t* __restrict__ Qh,
                                            const uint16_t* __restrict__ Kh,
                                            const uint16_t* __restrict__ Vh,
                                            uint16_t* __restrict__ Oh,
                                            float* __restrict__ Wlast) {
  __shared__ uint16_t Ks[128][72];   // pad 72 -> 144B rows, 2-way max conflict
  __shared__ uint16_t Vt[64][136];   // V transposed [d][token]
  __shared__ uint16_t Ps[128][136];  // softmax probs bf16

  const int blk = blockIdx.x;
  const int b = blk >> 10;           // H*G = 1024
  const int h = (blk >> 6) & 15;
  const int g = blk & 63;
  const size_t rowbase = (size_t)b * 8192 + (size_t)g * 128;
  const int colbase = h * 64;

  const int tid = threadIdx.x, lane = tid & 63, wv = tid >> 6;
  const int lc = lane & 15, lq = lane >> 4;
  const int m0 = wv * 32;

  // load K rows + V transposed into LDS
  {
    const int r = tid >> 1, hf = (tid & 1) * 32;
    const uint16_t* ksrc = Kh + (rowbase + r) * 1024 + colbase + hf;
    const uint16_t* vsrc = Vh + (rowbase + r) * 1024 + colbase + hf;
    union { uint16_t u[32]; uint4 v[4]; } kk, vb;
#pragma unroll
    for (int i = 0; i < 4; ++i) kk.v[i] = *(const uint4*)(ksrc + i * 8);
#pragma unroll
    for (int i = 0; i < 4; ++i) vb.v[i] = *(const uint4*)(vsrc + i * 8);
#pragma unroll
    for (int i = 0; i < 4; ++i) *(uint4*)&Ks[r][hf + i * 8] = kk.v[i];
#pragma unroll
    for (int j = 0; j < 32; ++j) Vt[hf + j][r] = vb.u[j];
  }

  // Q fragments straight from global (A-operand layout is 16B contiguous)
  bf16x8 aq[2][2];
#pragma unroll
  for (int mi = 0; mi < 2; ++mi)
#pragma unroll
    for (int ks = 0; ks < 2; ++ks)
      aq[mi][ks] = *(const bf16x8*)(Qh + (rowbase + m0 + mi * 16 + lc) * 1024 +
                                    colbase + ks * 32 + lq * 8);

  __syncthreads();

  // S = Q K^T  (per wave: 32 x 128)
  f32x4 sacc[2][8] = {};
#pragma unroll
  for (int ks = 0; ks < 2; ++ks) {
#pragma unroll
    for (int ni = 0; ni < 8; ++ni) {
      bf16x8 bk = *(const bf16x8*)&Ks[ni * 16 + lc][ks * 32 + lq * 8];
      sacc[0][ni] = MFMA16(aq[0][ks], bk, sacc[0][ni]);
      sacc[1][ni] = MFMA16(aq[1][ks], bk, sacc[1][ni]);
    }
  }

  // softmax over 128 cols; row = m0 + mi*16 + lq*4 + r, cols = ni*16 + lc
  const float scale = 0.125f;
  float mx[2][4], sm[2][4];
#pragma unroll
  for (int mi = 0; mi < 2; ++mi)
#pragma unroll
    for (int r = 0; r < 4; ++r) {
      float m = -1e30f;
#pragma unroll
      for (int ni = 0; ni < 8; ++ni) m = fmaxf(m, sacc[mi][ni][r]);
      m = fmaxf(m, __shfl_xor(m, 1));
      m = fmaxf(m, __shfl_xor(m, 2));
      m = fmaxf(m, __shfl_xor(m, 4));
      m = fmaxf(m, __shfl_xor(m, 8));
      mx[mi][r] = m * scale;
    }
#pragma unroll
  for (int mi = 0; mi < 2; ++mi)
#pragma unroll
    for (int ni = 0; ni < 8; ++ni)
#pragma unroll
      for (int r = 0; r < 4; ++r)
        sacc[mi][ni][r] = __expf(sacc[mi][ni][r] * scale - mx[mi][r]);
#pragma unroll
  for (int mi = 0; mi < 2; ++mi)
#pragma unroll
    for (int r = 0; r < 4; ++r) {
      float s = 0.f;
#pragma unroll
      for (int ni = 0; ni < 8; ++ni) s += sacc[mi][ni][r];
      s += __shfl_xor(s, 1); s += __shfl_xor(s, 2);
      s += __shfl_xor(s, 4); s += __shfl_xor(s, 8);
      sm[mi][r] = 1.0f / s;
    }

  // normalize, stash to LDS (bf16) for the PV A-operand
#pragma unroll
  for (int mi = 0; mi < 2; ++mi)
#pragma unroll
    for (int ni = 0; ni < 8; ++ni)
#pragma unroll
      for (int r = 0; r < 4; ++r) {
        float w = sacc[mi][ni][r] * sm[mi][r];
        sacc[mi][ni][r] = w;
        Ps[m0 + mi * 16 + lq * 4 + r][ni * 16 + lc] = f2bf(w);
      }
  if (g == 63) {   // emit output 1: softmax weights of last group, f32
    float* wl = Wlast + (size_t)(b * 16 + h) * 16384;
#pragma unroll
    for (int mi = 0; mi < 2; ++mi)
#pragma unroll
      for (int ni = 0; ni < 8; ++ni)
#pragma unroll
        for (int r = 0; r < 4; ++r)
          wl[(size_t)(m0 + mi * 16 + lq * 4 + r) * 128 + ni * 16 + lc] =
              sacc[mi][ni][r];
  }
  __syncthreads();

  // O = P V  (per wave: 32 x 64, K=128)
  f32x4 oacc[2][4] = {};
#pragma unroll
  for (int ks = 0; ks < 4; ++ks) {
    bf16x8 ap[2], bq[4];
#pragma unroll
    for (int mi = 0; mi < 2; ++mi)
      ap[mi] = *(const bf16x8*)&Ps[m0 + mi * 16 + lc][ks * 32 + lq * 8];
#pragma unroll
    for (int ni = 0; ni < 4; ++ni)
      bq[ni] = *(const bf16x8*)&Vt[ni * 16 + lc][ks * 32 + lq * 8];
#pragma unroll
    for (int mi = 0; mi < 2; ++mi)
#pragma unroll
      for (int ni = 0; ni < 4; ++ni)
        oacc[mi][ni] = MFMA16(ap[mi], bq[ni], oacc[mi][ni]);
  }
#pragma unroll
  for (int mi = 0; mi < 2; ++mi)
#pragma unroll
    for (int ni = 0; ni < 4; ++ni)
#pragma unroll
      for (int r = 0; r < 4; ++r)
        Oh[(rowbase + m0 + mi * 16 + lq * 4 + r) * 1024 + colbase + ni * 16 + lc] =
            f2bf(oacc[mi][ni][r]);
}

extern "C" void kernel_launch(void* const* d_in, const int* in_sizes, int n_in,
                              void* d_out, int out_size, void* d_ws, size_t ws_size,
                              hipStream_t stream) {
  (void)in_sizes; (void)n_in; (void)out_size; (void)ws_size;
  const float* q  = (const float*)d_in[0];
  const float* k  = (const float*)d_in[1];
  const float* v  = (const float*)d_in[2];
  const float* Wq = (const float*)d_in[3];
  const float* bq = (const float*)d_in[4];
  const float* Wk = (const float*)d_in[5];
  const float* bk = (const float*)d_in[6];
  const float* Wv = (const float*)d_in[7];
  const float* bv = (const float*)d_in[8];
  const float* Wo = (const float*)d_in[9];
  const float* bo = (const float*)d_in[10];

  uint8_t* ws = (uint8_t*)d_ws;
  const size_t WSZ = (size_t)1024 * 1024 * 2;   // 2 MB per transposed weight
  const size_t TSZ = (size_t)32768 * 1024 * 2;  // 64 MB per bf16 activation
  uint16_t* Wtq = (uint16_t*)(ws + 0 * WSZ);
  uint16_t* Wtk = (uint16_t*)(ws + 1 * WSZ);
  uint16_t* Wtv = (uint16_t*)(ws + 2 * WSZ);
  uint16_t* Wto = (uint16_t*)(ws + 3 * WSZ);
  uint16_t* Qh  = (uint16_t*)(ws + 4 * WSZ);
  uint16_t* Khp = (uint16_t*)(ws + 4 * WSZ + 1 * TSZ);
  uint16_t* Vhp = (uint16_t*)(ws + 4 * WSZ + 2 * TSZ);
  uint16_t* Xb  = (uint16_t*)(ws + 4 * WSZ + 3 * TSZ);  // staging / attn-out

  dim3 tb(256);
  wtrans<<<dim3(16, 16), tb, 0, stream>>>(Wq, Wtq);
  wtrans<<<dim3(16, 16), tb, 0, stream>>>(Wk, Wtk);
  wtrans<<<dim3(16, 16), tb, 0, stream>>>(Wv, Wtv);
  wtrans<<<dim3(16, 16), tb, 0, stream>>>(Wo, Wto);

  const long NE = (long)32768 * 1024;
  cvt_bf16<<<16384, tb, 0, stream>>>(q, Xb, NE);
  gemm_bt<<<dim3(8, 256), tb, 0, stream>>>(Xb, Wtq, bq, Qh, 0);
  cvt_bf16<<<16384, tb, 0, stream>>>(k, Xb, NE);
  gemm_bt<<<dim3(8, 256), tb, 0, stream>>>(Xb, Wtk, bk, Khp, 0);
  cvt_bf16<<<16384, tb, 0, stream>>>(v, Xb, NE);
  gemm_bt<<<dim3(8, 256), tb, 0, stream>>>(Xb, Wtv, bv, Vhp, 0);

  float* outp = (float*)d_out;
  attn<<<4096, tb, 0, stream>>>(Qh, Khp, Vhp, Xb, outp + (size_t)32768 * 1024);
  gemm_bt<<<dim3(8, 256), tb, 0, stream>>>(Xb, Wto, bo, outp, 1);
}

// Round 2
// 593.058 us; speedup vs baseline: 1.0879x; 1.0879x over previous
//
#include <hip/hip_runtime.h>
#include <stdint.h>

#define DEVI static __device__ __forceinline__

typedef __attribute__((ext_vector_type(8))) __bf16 bf16x8;
typedef __attribute__((ext_vector_type(4))) float f32x4;

#define MFMA16(a, b, c) __builtin_amdgcn_mfma_f32_16x16x32_bf16((a), (b), (c), 0, 0, 0)

DEVI uint16_t f2bf(float f) {
  uint32_t u = __builtin_bit_cast(uint32_t, f);
  u += 0x7fffu + ((u >> 16) & 1u);   // RNE (no NaN inputs here)
  return (uint16_t)(u >> 16);
}

DEVI void gload16(const void* g, void* l) {
  __builtin_amdgcn_global_load_lds((const __attribute__((address_space(1))) void*)g,
                                   (__attribute__((address_space(3))) void*)l, 16, 0, 0);
}

// ---------------- W f32 [1024][1024] -> Wt bf16 [n][k] (transposed) ----------------
__global__ __launch_bounds__(256) void wtrans(const float* __restrict__ W,
                                              uint16_t* __restrict__ Wt) {
  __shared__ float t[64][65];
  const int ti = blockIdx.y * 64, tj = blockIdx.x * 64;
  {
    int r = threadIdx.x >> 2, c0 = (threadIdx.x & 3) * 16;
#pragma unroll
    for (int i = 0; i < 16; i += 4) {
      float4 v = *(const float4*)(W + (size_t)(ti + r) * 1024 + tj + c0 + i);
      t[r][c0 + i + 0] = v.x; t[r][c0 + i + 1] = v.y;
      t[r][c0 + i + 2] = v.z; t[r][c0 + i + 3] = v.w;
    }
  }
  __syncthreads();
  {
    int c = threadIdx.x >> 2, r0 = (threadIdx.x & 3) * 16;
    union { uint16_t u[16]; uint4 v[2]; } b;
#pragma unroll
    for (int i = 0; i < 16; ++i) b.u[i] = f2bf(t[r0 + i][c]);
    uint16_t* dst = Wt + (size_t)(tj + c) * 1024 + ti + r0;
    *(uint4*)dst = b.v[0];
    *(uint4*)(dst + 8) = b.v[1];
  }
}

// ---------------- GEMM body: C[M][1024] = A[M][1024] @ Wt^T (+bias) ----------------
// AF32: A is f32, reg-staged (fused convert). else A bf16 via global_load_lds.
// 128x128 tile, BK=32, 4 waves, double-buffered LDS.
template <int AF32, int CF32>
DEVI void gemm_body(const void* __restrict__ Ap, const uint16_t* __restrict__ Bt,
                    const float* __restrict__ bias, void* __restrict__ C,
                    int mt, int nt, uint16_t* As, uint16_t* Bs) {
  const int tid = threadIdx.x;
  const int lane = tid & 63;
  const int wv = tid >> 6, wr = wv >> 1, wc = wv & 1;
  const int lc = lane & 15, lq = lane >> 4;
  const size_t m0 = (size_t)mt * 128;
  const int n0 = nt * 128;

  f32x4 acc[4][4] = {};
  const int o0 = tid * 16;  // byte offset inside an 8 KB LDS tile
  const uint8_t* Bb = (const uint8_t*)Bt + (size_t)n0 * 2048;
  const float* Af = (const float*)Ap;
  const uint8_t* Ab = (const uint8_t*)Ap + m0 * 2048;

  auto stageB = [&](int bsel, int kt) {
    const int k0b = kt * 64;
#pragma unroll
    for (int is = 0; is < 2; ++is) {
      int o = o0 + is * 4096;
      int row = o >> 6, kb = o & 63;
      gload16(Bb + (size_t)row * 2048 + k0b + kb, (uint8_t*)(Bs + bsel * 4096) + o);
    }
  };
  auto stageA_bf = [&](int bsel, int kt) {
    const int k0b = kt * 64;
#pragma unroll
    for (int is = 0; is < 2; ++is) {
      int o = o0 + is * 4096;
      int row = o >> 6, kb = o & 63;
      gload16(Ab + (size_t)row * 2048 + k0b + kb, (uint8_t*)(As + bsel * 4096) + o);
    }
  };
  auto loadA_f32 = [&](int kt, float4 (&ra)[2][2]) {
    const int k0 = kt * 32;
#pragma unroll
    for (int is = 0; is < 2; ++is) {
      int o = o0 + is * 4096;
      int row = o >> 6;
      int ke = (o & 63) >> 1;  // element offset in row: 0/8/16/24
      const float* src = Af + (size_t)(m0 + row) * 1024 + k0 + ke;
      ra[is][0] = *(const float4*)src;
      ra[is][1] = *(const float4*)(src + 4);
    }
  };
  auto writeA_f32 = [&](int bsel, float4 (&ra)[2][2]) {
#pragma unroll
    for (int is = 0; is < 2; ++is) {
      int o = o0 + is * 4096;
      const float* f = (const float*)&ra[is][0];
      union { uint16_t u[8]; uint4 v; } t;
#pragma unroll
      for (int j = 0; j < 8; ++j) t.u[j] = f2bf(f[j]);
      *(uint4*)((uint8_t*)(As + bsel * 4096) + o) = t.v;
    }
  };

  // prologue: stage tile 0
  if constexpr (AF32) {
    float4 r0[2][2];
    loadA_f32(0, r0);
    writeA_f32(0, r0);
  } else {
    stageA_bf(0, 0);
  }
  stageB(0, 0);

  int buf = 0;
  for (int kt = 0; kt < 32; ++kt) {
    __syncthreads();  // stage(kt) drained + prev-iter reads done
    float4 ra[2][2];
    const bool more = (kt + 1 < 32);
    if (more) {
      if constexpr (AF32) loadA_f32(kt + 1, ra);   // issue loads early
      else                stageA_bf(buf ^ 1, kt + 1);
      stageB(buf ^ 1, kt + 1);
    }
    const uint16_t* as = As + buf * 4096;
    const uint16_t* bs = Bs + buf * 4096;
    bf16x8 a[4], b[4];
#pragma unroll
    for (int i = 0; i < 4; ++i) {
      a[i] = *(const bf16x8*)(as + (wr * 64 + i * 16 + lc) * 32 + lq * 8);
      b[i] = *(const bf16x8*)(bs + (wc * 64 + i * 16 + lc) * 32 + lq * 8);
    }
#pragma unroll
    for (int mi = 0; mi < 4; ++mi)
#pragma unroll
      for (int ni = 0; ni < 4; ++ni)
        acc[mi][ni] = MFMA16(a[mi], b[ni], acc[mi][ni]);
    if constexpr (AF32) {
      if (more) writeA_f32(buf ^ 1, ra);  // convert+write late (hide HBM latency)
    }
    buf ^= 1;
  }

#pragma unroll
  for (int mi = 0; mi < 4; ++mi) {
#pragma unroll
    for (int ni = 0; ni < 4; ++ni) {
      const int col = n0 + wc * 64 + ni * 16 + lc;
      const float bb = bias[col];
#pragma unroll
      for (int r = 0; r < 4; ++r) {
        const size_t row = m0 + wr * 64 + mi * 16 + lq * 4 + r;
        float vv = acc[mi][ni][r] + bb;
        if constexpr (CF32) ((float*)C)[row * 1024 + col] = vv;
        else                ((uint16_t*)C)[row * 1024 + col] = f2bf(vv);
      }
    }
  }
}

struct Proj3 {
  const float* A[3];
  const uint16_t* W[3];
  const float* b[3];
  uint16_t* C[3];
};

// merged q/k/v projections; XCD-aware swizzle: XCD c owns M-panels [c*32,(c+1)*32)
__global__ __launch_bounds__(256) void gemm_proj3(Proj3 p) {
  __shared__ uint16_t As[2 * 4096];
  __shared__ uint16_t Bs[2 * 4096];
  const int bid = blockIdx.y * 8 + blockIdx.x;
  const int swz = (bid & 7) * 256 + (bid >> 3);
  const int z = blockIdx.z;
  gemm_body<1, 0>(p.A[z], p.W[z], p.b[z], p.C[z], swz >> 3, swz & 7, As, Bs);
}

__global__ __launch_bounds__(256) void gemm_final(const uint16_t* __restrict__ A,
                                                  const uint16_t* __restrict__ W,
                                                  const float* __restrict__ bias,
                                                  float* __restrict__ C) {
  __shared__ uint16_t As[2 * 4096];
  __shared__ uint16_t Bs[2 * 4096];
  const int bid = blockIdx.y * 8 + blockIdx.x;
  const int swz = (bid & 7) * 256 + (bid >> 3);
  gemm_body<0, 1>(A, W, bias, C, swz >> 3, swz & 7, As, Bs);
}

// ---------------- block-diagonal attention ----------------
// one block per (b,h,g); 4 waves, each owns 32 q-rows.
__global__ __launch_bounds__(256) void attn(const uint16_t* __restrict__ Qh,
                                            const uint16_t* __restrict__ Kh,
                                            const uint16_t* __restrict__ Vh,
                                            uint16_t* __restrict__ Oh,
                                            float* __restrict__ Wlast) {
  __shared__ uint16_t Ks[128][72];   // pad 72 -> 144B rows, 2-way max conflict
  __shared__ uint16_t Vt[64][136];   // V transposed [d][token]
  __shared__ uint16_t Ps[128][136];  // softmax probs bf16

  const int blk = blockIdx.x;
  const int b = blk >> 10;           // H*G = 1024
  const int h = (blk >> 6) & 15;
  const int g = blk & 63;
  const size_t rowbase = (size_t)b * 8192 + (size_t)g * 128;
  const int colbase = h * 64;

  const int tid = threadIdx.x, lane = tid & 63, wv = tid >> 6;
  const int lc = lane & 15, lq = lane >> 4;
  const int m0 = wv * 32;

  // load K rows + V transposed into LDS
  {
    const int r = tid >> 1, hf = (tid & 1) * 32;
    const uint16_t* ksrc = Kh + (rowbase + r) * 1024 + colbase + hf;
    const uint16_t* vsrc = Vh + (rowbase + r) * 1024 + colbase + hf;
    union { uint16_t u[32]; uint4 v[4]; } kk, vb;
#pragma unroll
    for (int i = 0; i < 4; ++i) kk.v[i] = *(const uint4*)(ksrc + i * 8);
#pragma unroll
    for (int i = 0; i < 4; ++i) vb.v[i] = *(const uint4*)(vsrc + i * 8);
#pragma unroll
    for (int i = 0; i < 4; ++i) *(uint4*)&Ks[r][hf + i * 8] = kk.v[i];
#pragma unroll
    for (int j = 0; j < 32; ++j) Vt[hf + j][r] = vb.u[j];
  }

  // Q fragments straight from global (A-operand layout is 16B contiguous)
  bf16x8 aq[2][2];
#pragma unroll
  for (int mi = 0; mi < 2; ++mi)
#pragma unroll
    for (int ks = 0; ks < 2; ++ks)
      aq[mi][ks] = *(const bf16x8*)(Qh + (rowbase + m0 + mi * 16 + lc) * 1024 +
                                    colbase + ks * 32 + lq * 8);

  __syncthreads();

  // S = Q K^T  (per wave: 32 x 128)
  f32x4 sacc[2][8] = {};
#pragma unroll
  for (int ks = 0; ks < 2; ++ks) {
#pragma unroll
    for (int ni = 0; ni < 8; ++ni) {
      bf16x8 bk = *(const bf16x8*)&Ks[ni * 16 + lc][ks * 32 + lq * 8];
      sacc[0][ni] = MFMA16(aq[0][ks], bk, sacc[0][ni]);
      sacc[1][ni] = MFMA16(aq[1][ks], bk, sacc[1][ni]);
    }
  }

  // softmax over 128 cols; row = m0 + mi*16 + lq*4 + r, cols = ni*16 + lc
  const float scale = 0.125f;
  float mx[2][4], sm[2][4];
#pragma unroll
  for (int mi = 0; mi < 2; ++mi)
#pragma unroll
    for (int r = 0; r < 4; ++r) {
      float m = -1e30f;
#pragma unroll
      for (int ni = 0; ni < 8; ++ni) m = fmaxf(m, sacc[mi][ni][r]);
      m = fmaxf(m, __shfl_xor(m, 1));
      m = fmaxf(m, __shfl_xor(m, 2));
      m = fmaxf(m, __shfl_xor(m, 4));
      m = fmaxf(m, __shfl_xor(m, 8));
      mx[mi][r] = m * scale;
    }
#pragma unroll
  for (int mi = 0; mi < 2; ++mi)
#pragma unroll
    for (int ni = 0; ni < 8; ++ni)
#pragma unroll
      for (int r = 0; r < 4; ++r)
        sacc[mi][ni][r] = __expf(sacc[mi][ni][r] * scale - mx[mi][r]);
#pragma unroll
  for (int mi = 0; mi < 2; ++mi)
#pragma unroll
    for (int r = 0; r < 4; ++r) {
      float s = 0.f;
#pragma unroll
      for (int ni = 0; ni < 8; ++ni) s += sacc[mi][ni][r];
      s += __shfl_xor(s, 1); s += __shfl_xor(s, 2);
      s += __shfl_xor(s, 4); s += __shfl_xor(s, 8);
      sm[mi][r] = 1.0f / s;
    }

  // normalize, stash to LDS (bf16) for the PV A-operand
#pragma unroll
  for (int mi = 0; mi < 2; ++mi)
#pragma unroll
    for (int ni = 0; ni < 8; ++ni)
#pragma unroll
      for (int r = 0; r < 4; ++r) {
        float w = sacc[mi][ni][r] * sm[mi][r];
        sacc[mi][ni][r] = w;
        Ps[m0 + mi * 16 + lq * 4 + r][ni * 16 + lc] = f2bf(w);
      }
  if (g == 63) {   // emit output 1: softmax weights of last group, f32
    float* wl = Wlast + (size_t)(b * 16 + h) * 16384;
#pragma unroll
    for (int mi = 0; mi < 2; ++mi)
#pragma unroll
      for (int ni = 0; ni < 8; ++ni)
#pragma unroll
        for (int r = 0; r < 4; ++r)
          wl[(size_t)(m0 + mi * 16 + lq * 4 + r) * 128 + ni * 16 + lc] =
              sacc[mi][ni][r];
  }
  __syncthreads();

  // O = P V  (per wave: 32 x 64, K=128)
  f32x4 oacc[2][4] = {};
#pragma unroll
  for (int ks = 0; ks < 4; ++ks) {
    bf16x8 ap[2], bq[4];
#pragma unroll
    for (int mi = 0; mi < 2; ++mi)
      ap[mi] = *(const bf16x8*)&Ps[m0 + mi * 16 + lc][ks * 32 + lq * 8];
#pragma unroll
    for (int ni = 0; ni < 4; ++ni)
      bq[ni] = *(const bf16x8*)&Vt[ni * 16 + lc][ks * 32 + lq * 8];
#pragma unroll
    for (int mi = 0; mi < 2; ++mi)
#pragma unroll
      for (int ni = 0; ni < 4; ++ni)
        oacc[mi][ni] = MFMA16(ap[mi], bq[ni], oacc[mi][ni]);
  }
#pragma unroll
  for (int mi = 0; mi < 2; ++mi)
#pragma unroll
    for (int ni = 0; ni < 4; ++ni)
#pragma unroll
      for (int r = 0; r < 4; ++r)
        Oh[(rowbase + m0 + mi * 16 + lq * 4 + r) * 1024 + colbase + ni * 16 + lc] =
            f2bf(oacc[mi][ni][r]);
}

extern "C" void kernel_launch(void* const* d_in, const int* in_sizes, int n_in,
                              void* d_out, int out_size, void* d_ws, size_t ws_size,
                              hipStream_t stream) {
  (void)in_sizes; (void)n_in; (void)out_size; (void)ws_size;
  const float* q  = (const float*)d_in[0];
  const float* k  = (const float*)d_in[1];
  const float* v  = (const float*)d_in[2];
  const float* Wq = (const float*)d_in[3];
  const float* bq = (const float*)d_in[4];
  const float* Wk = (const float*)d_in[5];
  const float* bk = (const float*)d_in[6];
  const float* Wv = (const float*)d_in[7];
  const float* bv = (const float*)d_in[8];
  const float* Wo = (const float*)d_in[9];
  const float* bo = (const float*)d_in[10];

  uint8_t* ws = (uint8_t*)d_ws;
  const size_t WSZ = (size_t)1024 * 1024 * 2;   // 2 MB per transposed weight
  const size_t TSZ = (size_t)32768 * 1024 * 2;  // 64 MB per bf16 activation
  uint16_t* Wtq = (uint16_t*)(ws + 0 * WSZ);
  uint16_t* Wtk = (uint16_t*)(ws + 1 * WSZ);
  uint16_t* Wtv = (uint16_t*)(ws + 2 * WSZ);
  uint16_t* Wto = (uint16_t*)(ws + 3 * WSZ);
  uint16_t* Qh  = (uint16_t*)(ws + 4 * WSZ);
  uint16_t* Khp = (uint16_t*)(ws + 4 * WSZ + 1 * TSZ);
  uint16_t* Vhp = (uint16_t*)(ws + 4 * WSZ + 2 * TSZ);
  uint16_t* Xb  = (uint16_t*)(ws + 4 * WSZ + 3 * TSZ);  // attn output (bf16)

  dim3 tb(256);
  wtrans<<<dim3(16, 16), tb, 0, stream>>>(Wq, Wtq);
  wtrans<<<dim3(16, 16), tb, 0, stream>>>(Wk, Wtk);
  wtrans<<<dim3(16, 16), tb, 0, stream>>>(Wv, Wtv);
  wtrans<<<dim3(16, 16), tb, 0, stream>>>(Wo, Wto);

  Proj3 p;
  p.A[0] = q;  p.A[1] = k;  p.A[2] = v;
  p.W[0] = Wtq; p.W[1] = Wtk; p.W[2] = Wtv;
  p.b[0] = bq; p.b[1] = bk; p.b[2] = bv;
  p.C[0] = Qh; p.C[1] = Khp; p.C[2] = Vhp;
  gemm_proj3<<<dim3(8, 256, 3), tb, 0, stream>>>(p);

  float* outp = (float*)d_out;
  attn<<<4096, tb, 0, stream>>>(Qh, Khp, Vhp, Xb, outp + (size_t)32768 * 1024);
  gemm_final<<<dim3(8, 256), tb, 0, stream>>>(Xb, Wto, bo, outp);
}

// Round 3
// 499.163 us; speedup vs baseline: 1.2925x; 1.1881x over previous
//
#include <hip/hip_runtime.h>
#include <stdint.h>

#define DEVI static __device__ __forceinline__

typedef __attribute__((ext_vector_type(8))) __bf16 bf16x8;
typedef __attribute__((ext_vector_type(4))) float f32x4;

#define MFMA16(a, b, c) __builtin_amdgcn_mfma_f32_16x16x32_bf16((a), (b), (c), 0, 0, 0)

DEVI uint16_t f2bf(float f) {
  uint32_t u = __builtin_bit_cast(uint32_t, f);
  u += 0x7fffu + ((u >> 16) & 1u);   // RNE (no NaN inputs here)
  return (uint16_t)(u >> 16);
}

DEVI void gload16(const void* g, void* l) {
  __builtin_amdgcn_global_load_lds((const __attribute__((address_space(1))) void*)g,
                                   (__attribute__((address_space(3))) void*)l, 16, 0, 0);
}

#define BARRIER()                         \
  do {                                    \
    __builtin_amdgcn_sched_barrier(0);    \
    __builtin_amdgcn_s_barrier();         \
    __builtin_amdgcn_sched_barrier(0);    \
  } while (0)

// ---------------- f32 -> bf16 convert (8 elems/thread) ----------------
__global__ __launch_bounds__(256) void cvt_bf16(const float* __restrict__ in,
                                                uint16_t* __restrict__ out, long n) {
  long i = ((long)blockIdx.x * 256 + threadIdx.x) * 8;
  if (i >= n) return;
  float4 a = *(const float4*)(in + i);
  float4 b = *(const float4*)(in + i + 4);
  union { uint16_t u[8]; uint4 v; } r;
  r.u[0] = f2bf(a.x); r.u[1] = f2bf(a.y); r.u[2] = f2bf(a.z); r.u[3] = f2bf(a.w);
  r.u[4] = f2bf(b.x); r.u[5] = f2bf(b.y); r.u[6] = f2bf(b.z); r.u[7] = f2bf(b.w);
  *(uint4*)(out + i) = r.v;
}

// ---------------- W f32 [1024][1024] -> Wt bf16 [n][k] (transposed) ----------------
__global__ __launch_bounds__(256) void wtrans(const float* __restrict__ W,
                                              uint16_t* __restrict__ Wt) {
  __shared__ float t[64][65];
  const int ti = blockIdx.y * 64, tj = blockIdx.x * 64;
  {
    int r = threadIdx.x >> 2, c0 = (threadIdx.x & 3) * 16;
#pragma unroll
    for (int i = 0; i < 16; i += 4) {
      float4 v = *(const float4*)(W + (size_t)(ti + r) * 1024 + tj + c0 + i);
      t[r][c0 + i + 0] = v.x; t[r][c0 + i + 1] = v.y;
      t[r][c0 + i + 2] = v.z; t[r][c0 + i + 3] = v.w;
    }
  }
  __syncthreads();
  {
    int c = threadIdx.x >> 2, r0 = (threadIdx.x & 3) * 16;
    union { uint16_t u[16]; uint4 v[2]; } b;
#pragma unroll
    for (int i = 0; i < 16; ++i) b.u[i] = f2bf(t[r0 + i][c]);
    uint16_t* dst = Wt + (size_t)(tj + c) * 1024 + ti + r0;
    *(uint4*)dst = b.v[0];
    *(uint4*)(dst + 8) = b.v[1];
  }
}

// ---------------- 256x256-tile GEMM, BK=32, 8 waves, 4-deep counted-vmcnt ----------------
// C[M][1024] = A[M][1024] @ Bt^T (+bias).  A,Bt bf16; C f32 or bf16.
// LDS: A 4x16KB + B 4x16KB = 128KB.  Stage tile kt+3 during iter kt; wait
// vmcnt(8) at end of iter (tile kt+1 landed, tiles kt+2/kt+3 stay in flight).
// LDS tile [256][32] bf16 (64B rows), XOR swizzle: colbyte ^= ((row>>1)&3)<<4,
// applied inverse on the global_load_lds SOURCE (linear LDS dest) and forward
// on the ds_read address (rule #21).
__global__ __launch_bounds__(512, 2) void gemm256(const uint16_t* __restrict__ A,
                                                  const uint16_t* __restrict__ Bt,
                                                  const float* __restrict__ bias,
                                                  void* __restrict__ C, int cf32) {
  __shared__ uint8_t lds[131072];
  const int tid = threadIdx.x;
  const int l = tid & 63, w = tid >> 6;
  const int wr = w >> 2, wc = w & 3;     // 2 x 4 wave grid
  const int lc = l & 15, lq = l >> 4;

  // bijective XCD swizzle over 512 blocks: XCD c owns mt in [c*16, c*16+16)
  const int bid = blockIdx.y * 4 + blockIdx.x;
  const int swz = (bid & 7) * 64 + (bid >> 3);
  const size_t m0 = (size_t)(swz >> 2) * 256;
  const int n0 = (swz & 3) * 256;

  const uint8_t* Ab = (const uint8_t*)A + m0 * 2048;
  const uint8_t* Bb = (const uint8_t*)Bt + (size_t)n0 * 2048;

  // staging geometry: chunk c = w*2+j (1KB each, 16 rows); lane l covers 16B
  const int crow = l >> 2;                             // row within chunk
  const int csw = 16 * ((l & 3) ^ ((l >> 3) & 3));     // inverse-swizzled col byte

  auto stageA = [&](int sb, int kt) {
#pragma unroll
    for (int j = 0; j < 2; ++j) {
      const int c = w * 2 + j;
      gload16(Ab + (size_t)(c * 16 + crow) * 2048 + kt * 64 + csw,
              lds + sb * 16384 + c * 1024);
    }
  };
  auto stageB = [&](int sb, int kt) {
#pragma unroll
    for (int j = 0; j < 2; ++j) {
      const int c = w * 2 + j;
      gload16(Bb + (size_t)(c * 16 + crow) * 2048 + kt * 64 + csw,
              lds + 65536 + sb * 16384 + c * 1024);
    }
  };

  // fragment reads (swizzled): sel depends only on lc
  const int sel = ((lc >> 1) & 3) << 4;
  auto ldsA = [&](int bf, int mi) -> bf16x8 {
    const int row = wr * 128 + mi * 16 + lc;
    return *(const bf16x8*)(lds + bf * 16384 + row * 64 + ((lq * 16) ^ sel));
  };
  auto ldsB = [&](int bf, int ni) -> bf16x8 {
    const int row = wc * 64 + ni * 16 + lc;
    return *(const bf16x8*)(lds + 65536 + bf * 16384 + row * 64 + ((lq * 16) ^ sel));
  };

  f32x4 acc[8][4] = {};
  bf16x8 aF[8], bF[4];

  // prologue: stage tiles 0,1,2 (12 loads); wait until tile 0 landed
  stageA(0, 0); stageB(0, 0);
  stageA(1, 1); stageB(1, 1);
  stageA(2, 2); stageB(2, 2);
  asm volatile("s_waitcnt vmcnt(8)" ::: "memory");
  BARRIER();

  for (int kt = 0; kt < 32; ++kt) {
    const int bf = kt & 3;
    const int sb = (kt + 3) & 3;
    const bool st = (kt + 3) < 32;

    if (st) stageA(sb, kt + 3);
    // phase 1: all A frags + B frags 0,1 -> 16 MFMA
#pragma unroll
    for (int mi = 0; mi < 8; ++mi) aF[mi] = ldsA(bf, mi);
#pragma unroll
    for (int ni = 0; ni < 2; ++ni) bF[ni] = ldsB(bf, ni);
    __builtin_amdgcn_s_setprio(1);
#pragma unroll
    for (int mi = 0; mi < 8; ++mi)
#pragma unroll
      for (int ni = 0; ni < 2; ++ni)
        acc[mi][ni] = MFMA16(aF[mi], bF[ni], acc[mi][ni]);
    __builtin_amdgcn_s_setprio(0);

    if (st) stageB(sb, kt + 3);
    // phase 2: B frags 2,3 -> 16 MFMA
#pragma unroll
    for (int ni = 2; ni < 4; ++ni) bF[ni] = ldsB(bf, ni);
    __builtin_amdgcn_s_setprio(1);
#pragma unroll
    for (int mi = 0; mi < 8; ++mi)
#pragma unroll
      for (int ni = 2; ni < 4; ++ni)
        acc[mi][ni] = MFMA16(aF[mi], bF[ni], acc[mi][ni]);
    __builtin_amdgcn_s_setprio(0);

    // counted wait: tile kt+1 landed; kt+2/kt+3 stay in flight
    if (kt < 29)       { asm volatile("s_waitcnt vmcnt(8)" ::: "memory"); }
    else if (kt == 29) { asm volatile("s_waitcnt vmcnt(4)" ::: "memory"); }
    else if (kt == 30) { asm volatile("s_waitcnt vmcnt(0)" ::: "memory"); }
    if (kt < 31) BARRIER();
  }

  // epilogue: bias + store
#pragma unroll
  for (int mi = 0; mi < 8; ++mi) {
#pragma unroll
    for (int ni = 0; ni < 4; ++ni) {
      const int col = n0 + wc * 64 + ni * 16 + lc;
      const float bb = bias[col];
#pragma unroll
      for (int r = 0; r < 4; ++r) {
        const size_t row = m0 + wr * 128 + mi * 16 + lq * 4 + r;
        const float vv = acc[mi][ni][r] + bb;
        if (cf32) ((float*)C)[row * 1024 + col] = vv;
        else      ((uint16_t*)C)[row * 1024 + col] = f2bf(vv);
      }
    }
  }
}

// ---------------- block-diagonal attention ----------------
// one block per (b,h,g); 4 waves, each owns 32 q-rows.
__global__ __launch_bounds__(256) void attn(const uint16_t* __restrict__ Qh,
                                            const uint16_t* __restrict__ Kh,
                                            const uint16_t* __restrict__ Vh,
                                            uint16_t* __restrict__ Oh,
                                            float* __restrict__ Wlast) {
  __shared__ uint16_t Ks[128][72];
  __shared__ uint16_t Vt[64][136];
  __shared__ uint16_t Ps[128][136];

  const int blk = blockIdx.x;
  const int b = blk >> 10;
  const int h = (blk >> 6) & 15;
  const int g = blk & 63;
  const size_t rowbase = (size_t)b * 8192 + (size_t)g * 128;
  const int colbase = h * 64;

  const int tid = threadIdx.x, lane = tid & 63, wv = tid >> 6;
  const int lc = lane & 15, lq = lane >> 4;
  const int m0 = wv * 32;

  {
    const int r = tid >> 1, hf = (tid & 1) * 32;
    const uint16_t* ksrc = Kh + (rowbase + r) * 1024 + colbase + hf;
    const uint16_t* vsrc = Vh + (rowbase + r) * 1024 + colbase + hf;
    union { uint16_t u[32]; uint4 v[4]; } kk, vb;
#pragma unroll
    for (int i = 0; i < 4; ++i) kk.v[i] = *(const uint4*)(ksrc + i * 8);
#pragma unroll
    for (int i = 0; i < 4; ++i) vb.v[i] = *(const uint4*)(vsrc + i * 8);
#pragma unroll
    for (int i = 0; i < 4; ++i) *(uint4*)&Ks[r][hf + i * 8] = kk.v[i];
#pragma unroll
    for (int j = 0; j < 32; ++j) Vt[hf + j][r] = vb.u[j];
  }

  bf16x8 aq[2][2];
#pragma unroll
  for (int mi = 0; mi < 2; ++mi)
#pragma unroll
    for (int ks = 0; ks < 2; ++ks)
      aq[mi][ks] = *(const bf16x8*)(Qh + (rowbase + m0 + mi * 16 + lc) * 1024 +
                                    colbase + ks * 32 + lq * 8);

  __syncthreads();

  f32x4 sacc[2][8] = {};
#pragma unroll
  for (int ks = 0; ks < 2; ++ks) {
#pragma unroll
    for (int ni = 0; ni < 8; ++ni) {
      bf16x8 bk = *(const bf16x8*)&Ks[ni * 16 + lc][ks * 32 + lq * 8];
      sacc[0][ni] = MFMA16(aq[0][ks], bk, sacc[0][ni]);
      sacc[1][ni] = MFMA16(aq[1][ks], bk, sacc[1][ni]);
    }
  }

  const float scale = 0.125f;
  float mx[2][4], sm[2][4];
#pragma unroll
  for (int mi = 0; mi < 2; ++mi)
#pragma unroll
    for (int r = 0; r < 4; ++r) {
      float m = -1e30f;
#pragma unroll
      for (int ni = 0; ni < 8; ++ni) m = fmaxf(m, sacc[mi][ni][r]);
      m = fmaxf(m, __shfl_xor(m, 1));
      m = fmaxf(m, __shfl_xor(m, 2));
      m = fmaxf(m, __shfl_xor(m, 4));
      m = fmaxf(m, __shfl_xor(m, 8));
      mx[mi][r] = m * scale;
    }
#pragma unroll
  for (int mi = 0; mi < 2; ++mi)
#pragma unroll
    for (int ni = 0; ni < 8; ++ni)
#pragma unroll
      for (int r = 0; r < 4; ++r)
        sacc[mi][ni][r] = __expf(sacc[mi][ni][r] * scale - mx[mi][r]);
#pragma unroll
  for (int mi = 0; mi < 2; ++mi)
#pragma unroll
    for (int r = 0; r < 4; ++r) {
      float s = 0.f;
#pragma unroll
      for (int ni = 0; ni < 8; ++ni) s += sacc[mi][ni][r];
      s += __shfl_xor(s, 1); s += __shfl_xor(s, 2);
      s += __shfl_xor(s, 4); s += __shfl_xor(s, 8);
      sm[mi][r] = 1.0f / s;
    }

#pragma unroll
  for (int mi = 0; mi < 2; ++mi)
#pragma unroll
    for (int ni = 0; ni < 8; ++ni)
#pragma unroll
      for (int r = 0; r < 4; ++r) {
        float wgt = sacc[mi][ni][r] * sm[mi][r];
        sacc[mi][ni][r] = wgt;
        Ps[m0 + mi * 16 + lq * 4 + r][ni * 16 + lc] = f2bf(wgt);
      }
  if (g == 63) {
    float* wl = Wlast + (size_t)(b * 16 + h) * 16384;
#pragma unroll
    for (int mi = 0; mi < 2; ++mi)
#pragma unroll
      for (int ni = 0; ni < 8; ++ni)
#pragma unroll
        for (int r = 0; r < 4; ++r)
          wl[(size_t)(m0 + mi * 16 + lq * 4 + r) * 128 + ni * 16 + lc] =
              sacc[mi][ni][r];
  }
  __syncthreads();

  f32x4 oacc[2][4] = {};
#pragma unroll
  for (int ks = 0; ks < 4; ++ks) {
    bf16x8 ap[2], bq[4];
#pragma unroll
    for (int mi = 0; mi < 2; ++mi)
      ap[mi] = *(const bf16x8*)&Ps[m0 + mi * 16 + lc][ks * 32 + lq * 8];
#pragma unroll
    for (int ni = 0; ni < 4; ++ni)
      bq[ni] = *(const bf16x8*)&Vt[ni * 16 + lc][ks * 32 + lq * 8];
#pragma unroll
    for (int mi = 0; mi < 2; ++mi)
#pragma unroll
      for (int ni = 0; ni < 4; ++ni)
        oacc[mi][ni] = MFMA16(ap[mi], bq[ni], oacc[mi][ni]);
  }
#pragma unroll
  for (int mi = 0; mi < 2; ++mi)
#pragma unroll
    for (int ni = 0; ni < 4; ++ni)
#pragma unroll
      for (int r = 0; r < 4; ++r)
        Oh[(rowbase + m0 + mi * 16 + lq * 4 + r) * 1024 + colbase + ni * 16 + lc] =
            f2bf(oacc[mi][ni][r]);
}

extern "C" void kernel_launch(void* const* d_in, const int* in_sizes, int n_in,
                              void* d_out, int out_size, void* d_ws, size_t ws_size,
                              hipStream_t stream) {
  (void)in_sizes; (void)n_in; (void)out_size; (void)ws_size;
  const float* q  = (const float*)d_in[0];
  const float* k  = (const float*)d_in[1];
  const float* v  = (const float*)d_in[2];
  const float* Wq = (const float*)d_in[3];
  const float* bq = (const float*)d_in[4];
  const float* Wk = (const float*)d_in[5];
  const float* bk = (const float*)d_in[6];
  const float* Wv = (const float*)d_in[7];
  const float* bv = (const float*)d_in[8];
  const float* Wo = (const float*)d_in[9];
  const float* bo = (const float*)d_in[10];

  uint8_t* ws = (uint8_t*)d_ws;
  const size_t WSZ = (size_t)1024 * 1024 * 2;   // 2 MB per transposed weight
  const size_t TSZ = (size_t)32768 * 1024 * 2;  // 64 MB per bf16 activation
  uint16_t* Wtq = (uint16_t*)(ws + 0 * WSZ);
  uint16_t* Wtk = (uint16_t*)(ws + 1 * WSZ);
  uint16_t* Wtv = (uint16_t*)(ws + 2 * WSZ);
  uint16_t* Wto = (uint16_t*)(ws + 3 * WSZ);
  uint16_t* Qh  = (uint16_t*)(ws + 4 * WSZ);
  uint16_t* Khp = (uint16_t*)(ws + 4 * WSZ + 1 * TSZ);
  uint16_t* Vhp = (uint16_t*)(ws + 4 * WSZ + 2 * TSZ);
  uint16_t* Xs  = (uint16_t*)(ws + 4 * WSZ + 3 * TSZ);  // staging / attn-out

  dim3 tb(256);
  wtrans<<<dim3(16, 16), tb, 0, stream>>>(Wq, Wtq);
  wtrans<<<dim3(16, 16), tb, 0, stream>>>(Wk, Wtk);
  wtrans<<<dim3(16, 16), tb, 0, stream>>>(Wv, Wtv);
  wtrans<<<dim3(16, 16), tb, 0, stream>>>(Wo, Wto);

  const long NE = (long)32768 * 1024;
  const dim3 gg(4, 128), gb(512);
  cvt_bf16<<<16384, tb, 0, stream>>>(q, Xs, NE);
  gemm256<<<gg, gb, 0, stream>>>(Xs, Wtq, bq, Qh, 0);
  cvt_bf16<<<16384, tb, 0, stream>>>(k, Xs, NE);
  gemm256<<<gg, gb, 0, stream>>>(Xs, Wtk, bk, Khp, 0);
  cvt_bf16<<<16384, tb, 0, stream>>>(v, Xs, NE);
  gemm256<<<gg, gb, 0, stream>>>(Xs, Wtv, bv, Vhp, 0);

  float* outp = (float*)d_out;
  attn<<<4096, tb, 0, stream>>>(Qh, Khp, Vhp, Xs, outp + (size_t)32768 * 1024);
  gemm256<<<gg, gb, 0, stream>>>(Xs, Wto, bo, outp, 1);
}

// Round 4
// 497.532 us; speedup vs baseline: 1.2968x; 1.0033x over previous
//
#include <hip/hip_runtime.h>
#include <stdint.h>

#define DEVI static __device__ __forceinline__

typedef __attribute__((ext_vector_type(8))) __bf16 bf16x8;
typedef __attribute__((ext_vector_type(4))) float f32x4;

#define MFMA16(a, b, c) __builtin_amdgcn_mfma_f32_16x16x32_bf16((a), (b), (c), 0, 0, 0)

DEVI uint16_t f2bf(float f) {
  uint32_t u = __builtin_bit_cast(uint32_t, f);
  u += 0x7fffu + ((u >> 16) & 1u);   // RNE (no NaN inputs here)
  return (uint16_t)(u >> 16);
}

DEVI void gload16(const void* g, void* l) {
  __builtin_amdgcn_global_load_lds((const __attribute__((address_space(1))) void*)g,
                                   (__attribute__((address_space(3))) void*)l, 16, 0, 0);
}

#define BARRIER()                         \
  do {                                    \
    __builtin_amdgcn_sched_barrier(0);    \
    __builtin_amdgcn_s_barrier();         \
    __builtin_amdgcn_sched_barrier(0);    \
  } while (0)

// ---------------- f32 -> bf16 convert (8 elems/thread) ----------------
__global__ __launch_bounds__(256) void cvt_bf16(const float* __restrict__ in,
                                                uint16_t* __restrict__ out, long n) {
  long i = ((long)blockIdx.x * 256 + threadIdx.x) * 8;
  if (i >= n) return;
  float4 a = *(const float4*)(in + i);
  float4 b = *(const float4*)(in + i + 4);
  union { uint16_t u[8]; uint4 v; } r;
  r.u[0] = f2bf(a.x); r.u[1] = f2bf(a.y); r.u[2] = f2bf(a.z); r.u[3] = f2bf(a.w);
  r.u[4] = f2bf(b.x); r.u[5] = f2bf(b.y); r.u[6] = f2bf(b.z); r.u[7] = f2bf(b.w);
  *(uint4*)(out + i) = r.v;
}

// ---------------- W f32 [1024][1024] -> Wt bf16 [n][k] (transposed) ----------------
__global__ __launch_bounds__(256) void wtrans(const float* __restrict__ W,
                                              uint16_t* __restrict__ Wt) {
  __shared__ float t[64][65];
  const int ti = blockIdx.y * 64, tj = blockIdx.x * 64;
  {
    int r = threadIdx.x >> 2, c0 = (threadIdx.x & 3) * 16;
#pragma unroll
    for (int i = 0; i < 16; i += 4) {
      float4 v = *(const float4*)(W + (size_t)(ti + r) * 1024 + tj + c0 + i);
      t[r][c0 + i + 0] = v.x; t[r][c0 + i + 1] = v.y;
      t[r][c0 + i + 2] = v.z; t[r][c0 + i + 3] = v.w;
    }
  }
  __syncthreads();
  {
    int c = threadIdx.x >> 2, r0 = (threadIdx.x & 3) * 16;
    union { uint16_t u[16]; uint4 v[2]; } b;
#pragma unroll
    for (int i = 0; i < 16; ++i) b.u[i] = f2bf(t[r0 + i][c]);
    uint16_t* dst = Wt + (size_t)(tj + c) * 1024 + ti + r0;
    *(uint4*)dst = b.v[0];
    *(uint4*)(dst + 8) = b.v[1];
  }
}

// ---------------- 256x256-tile GEMM, BK=32, 8 waves, 4-deep counted-vmcnt ----------------
// Template-density phases (m201 port): per K-step, 2 phases of
// {ds_read subtile ; stage 1 chunk ; BAR ; setprio1 ; 16 MFMA ; setprio0 ; BAR}.
// vmcnt(8) once per K-step (2 tiles stay in flight, never drained to 0).
// LDS tile [256][32] bf16 (64B rows), XOR swizzle (proven: 0 bank conflicts):
// inverse on global_load_lds SOURCE, forward on ds_read address.
__global__ __launch_bounds__(512, 2) void gemm256(const uint16_t* __restrict__ A,
                                                  const uint16_t* __restrict__ Bt,
                                                  const float* __restrict__ bias,
                                                  void* __restrict__ C, int cf32) {
  __shared__ uint8_t lds[131072];
  const int tid = threadIdx.x;
  const int l = tid & 63, w = tid >> 6;
  const int wr = w >> 2, wc = w & 3;     // 2 x 4 wave grid
  const int lc = l & 15, lq = l >> 4;

  // bijective XCD swizzle over 512 blocks: XCD c owns mt in [c*16, c*16+16)
  const int bid = blockIdx.y * 4 + blockIdx.x;
  const int swz = (bid & 7) * 64 + (bid >> 3);
  const size_t m0 = (size_t)(swz >> 2) * 256;
  const int n0 = (swz & 3) * 256;

  const uint8_t* Ab = (const uint8_t*)A + m0 * 2048;
  const uint8_t* Bb = (const uint8_t*)Bt + (size_t)n0 * 2048;

  // staging geometry: chunk c = w*2+j (1KB each, 16 rows); lane l covers 16B
  const int crow = l >> 2;                             // row within chunk
  const int csw = 16 * ((l & 3) ^ ((l >> 3) & 3));     // inverse-swizzled col byte

  auto stageA = [&](int sb, int kt) {
#pragma unroll
    for (int j = 0; j < 2; ++j) {
      const int c = w * 2 + j;
      gload16(Ab + (size_t)(c * 16 + crow) * 2048 + kt * 64 + csw,
              lds + sb * 16384 + c * 1024);
    }
  };
  auto stageB = [&](int sb, int kt) {
#pragma unroll
    for (int j = 0; j < 2; ++j) {
      const int c = w * 2 + j;
      gload16(Bb + (size_t)(c * 16 + crow) * 2048 + kt * 64 + csw,
              lds + 65536 + sb * 16384 + c * 1024);
    }
  };

  // fragment reads (swizzled): sel depends only on lc
  const int sel = ((lc >> 1) & 3) << 4;
  auto ldsA = [&](int bf, int mi) -> bf16x8 {
    const int row = wr * 128 + mi * 16 + lc;
    return *(const bf16x8*)(lds + bf * 16384 + row * 64 + ((lq * 16) ^ sel));
  };
  auto ldsB = [&](int bf, int ni) -> bf16x8 {
    const int row = wc * 64 + ni * 16 + lc;
    return *(const bf16x8*)(lds + 65536 + bf * 16384 + row * 64 + ((lq * 16) ^ sel));
  };

  f32x4 acc[8][4] = {};
  bf16x8 aF[8], bF[4];

  // prologue: stage tiles 0,1,2 (12 loads); wait until tile 0 landed
  stageA(0, 0); stageB(0, 0);
  stageA(1, 1); stageB(1, 1);
  stageA(2, 2); stageB(2, 2);
  asm volatile("s_waitcnt vmcnt(8)" ::: "memory");
  BARRIER();

  for (int kt = 0; kt < 32; ++kt) {
    const int bf = kt & 3;
    const int sb = (kt + 3) & 3;
    const bool st = (kt + 3) < 32;

    // ---- phase 0: {reads B01+A0-7 ; stage A ; BAR ; 16 MFMA ; BAR} ----
    bF[0] = ldsB(bf, 0);
    bF[1] = ldsB(bf, 1);
#pragma unroll
    for (int mi = 0; mi < 8; ++mi) aF[mi] = ldsA(bf, mi);
    if (st) stageA(sb, kt + 3);
    BARRIER();
    __builtin_amdgcn_s_setprio(1);
#pragma unroll
    for (int mi = 0; mi < 8; ++mi) {
      acc[mi][0] = MFMA16(aF[mi], bF[0], acc[mi][0]);
      acc[mi][1] = MFMA16(aF[mi], bF[1], acc[mi][1]);
    }
    __builtin_amdgcn_s_setprio(0);
    BARRIER();

    // ---- phase 1: {reads B23 ; stage B ; vmcnt ; BAR ; 16 MFMA ; BAR} ----
    bF[2] = ldsB(bf, 2);
    bF[3] = ldsB(bf, 3);
    if (st) stageB(sb, kt + 3);
    if (kt < 29)       { asm volatile("s_waitcnt vmcnt(8)" ::: "memory"); }
    else if (kt == 29) { asm volatile("s_waitcnt vmcnt(4)" ::: "memory"); }
    else if (kt == 30) { asm volatile("s_waitcnt vmcnt(0)" ::: "memory"); }
    __builtin_amdgcn_sched_barrier(0);
    BARRIER();
    __builtin_amdgcn_s_setprio(1);
#pragma unroll
    for (int mi = 0; mi < 8; ++mi) {
      acc[mi][2] = MFMA16(aF[mi], bF[2], acc[mi][2]);
      acc[mi][3] = MFMA16(aF[mi], bF[3], acc[mi][3]);
    }
    __builtin_amdgcn_s_setprio(0);
    if (kt < 31) BARRIER();
  }

  // epilogue: bias + store
#pragma unroll
  for (int mi = 0; mi < 8; ++mi) {
#pragma unroll
    for (int ni = 0; ni < 4; ++ni) {
      const int col = n0 + wc * 64 + ni * 16 + lc;
      const float bb = bias[col];
#pragma unroll
      for (int r = 0; r < 4; ++r) {
        const size_t row = m0 + wr * 128 + mi * 16 + lq * 4 + r;
        const float vv = acc[mi][ni][r] + bb;
        if (cf32) ((float*)C)[row * 1024 + col] = vv;
        else      ((uint16_t*)C)[row * 1024 + col] = f2bf(vv);
      }
    }
  }
}

// ---------------- block-diagonal attention ----------------
// one block per (b,h,g); 4 waves, each owns 32 q-rows.
__global__ __launch_bounds__(256) void attn(const uint16_t* __restrict__ Qh,
                                            const uint16_t* __restrict__ Kh,
                                            const uint16_t* __restrict__ Vh,
                                            uint16_t* __restrict__ Oh,
                                            float* __restrict__ Wlast) {
  __shared__ uint16_t Ks[128][72];
  __shared__ uint16_t Vt[64][136];
  __shared__ uint16_t Ps[128][136];

  const int blk = blockIdx.x;
  const int b = blk >> 10;
  const int h = (blk >> 6) & 15;
  const int g = blk & 63;
  const size_t rowbase = (size_t)b * 8192 + (size_t)g * 128;
  const int colbase = h * 64;

  const int tid = threadIdx.x, lane = tid & 63, wv = tid >> 6;
  const int lc = lane & 15, lq = lane >> 4;
  const int m0 = wv * 32;

  {
    const int r = tid >> 1, hf = (tid & 1) * 32;
    const uint16_t* ksrc = Kh + (rowbase + r) * 1024 + colbase + hf;
    const uint16_t* vsrc = Vh + (rowbase + r) * 1024 + colbase + hf;
    union { uint16_t u[32]; uint4 v[4]; } kk, vb;
#pragma unroll
    for (int i = 0; i < 4; ++i) kk.v[i] = *(const uint4*)(ksrc + i * 8);
#pragma unroll
    for (int i = 0; i < 4; ++i) vb.v[i] = *(const uint4*)(vsrc + i * 8);
#pragma unroll
    for (int i = 0; i < 4; ++i) *(uint4*)&Ks[r][hf + i * 8] = kk.v[i];
#pragma unroll
    for (int j = 0; j < 32; ++j) Vt[hf + j][r] = vb.u[j];
  }

  bf16x8 aq[2][2];
#pragma unroll
  for (int mi = 0; mi < 2; ++mi)
#pragma unroll
    for (int ks = 0; ks < 2; ++ks)
      aq[mi][ks] = *(const bf16x8*)(Qh + (rowbase + m0 + mi * 16 + lc) * 1024 +
                                    colbase + ks * 32 + lq * 8);

  __syncthreads();

  f32x4 sacc[2][8] = {};
#pragma unroll
  for (int ks = 0; ks < 2; ++ks) {
#pragma unroll
    for (int ni = 0; ni < 8; ++ni) {
      bf16x8 bk = *(const bf16x8*)&Ks[ni * 16 + lc][ks * 32 + lq * 8];
      sacc[0][ni] = MFMA16(aq[0][ks], bk, sacc[0][ni]);
      sacc[1][ni] = MFMA16(aq[1][ks], bk, sacc[1][ni]);
    }
  }

  const float scale = 0.125f;
  float mx[2][4], sm[2][4];
#pragma unroll
  for (int mi = 0; mi < 2; ++mi)
#pragma unroll
    for (int r = 0; r < 4; ++r) {
      float m = -1e30f;
#pragma unroll
      for (int ni = 0; ni < 8; ++ni) m = fmaxf(m, sacc[mi][ni][r]);
      m = fmaxf(m, __shfl_xor(m, 1));
      m = fmaxf(m, __shfl_xor(m, 2));
      m = fmaxf(m, __shfl_xor(m, 4));
      m = fmaxf(m, __shfl_xor(m, 8));
      mx[mi][r] = m * scale;
    }
#pragma unroll
  for (int mi = 0; mi < 2; ++mi)
#pragma unroll
    for (int ni = 0; ni < 8; ++ni)
#pragma unroll
      for (int r = 0; r < 4; ++r)
        sacc[mi][ni][r] = __expf(sacc[mi][ni][r] * scale - mx[mi][r]);
#pragma unroll
  for (int mi = 0; mi < 2; ++mi)
#pragma unroll
    for (int r = 0; r < 4; ++r) {
      float s = 0.f;
#pragma unroll
      for (int ni = 0; ni < 8; ++ni) s += sacc[mi][ni][r];
      s += __shfl_xor(s, 1); s += __shfl_xor(s, 2);
      s += __shfl_xor(s, 4); s += __shfl_xor(s, 8);
      sm[mi][r] = 1.0f / s;
    }

#pragma unroll
  for (int mi = 0; mi < 2; ++mi)
#pragma unroll
    for (int ni = 0; ni < 8; ++ni)
#pragma unroll
      for (int r = 0; r < 4; ++r) {
        float wgt = sacc[mi][ni][r] * sm[mi][r];
        sacc[mi][ni][r] = wgt;
        Ps[m0 + mi * 16 + lq * 4 + r][ni * 16 + lc] = f2bf(wgt);
      }
  if (g == 63) {
    float* wl = Wlast + (size_t)(b * 16 + h) * 16384;
#pragma unroll
    for (int mi = 0; mi < 2; ++mi)
#pragma unroll
      for (int ni = 0; ni < 8; ++ni)
#pragma unroll
        for (int r = 0; r < 4; ++r)
          wl[(size_t)(m0 + mi * 16 + lq * 4 + r) * 128 + ni * 16 + lc] =
              sacc[mi][ni][r];
  }
  __syncthreads();

  f32x4 oacc[2][4] = {};
#pragma unroll
  for (int ks = 0; ks < 4; ++ks) {
    bf16x8 ap[2], bq[4];
#pragma unroll
    for (int mi = 0; mi < 2; ++mi)
      ap[mi] = *(const bf16x8*)&Ps[m0 + mi * 16 + lc][ks * 32 + lq * 8];
#pragma unroll
    for (int ni = 0; ni < 4; ++ni)
      bq[ni] = *(const bf16x8*)&Vt[ni * 16 + lc][ks * 32 + lq * 8];
#pragma unroll
    for (int mi = 0; mi < 2; ++mi)
#pragma unroll
      for (int ni = 0; ni < 4; ++ni)
        oacc[mi][ni] = MFMA16(ap[mi], bq[ni], oacc[mi][ni]);
  }
#pragma unroll
  for (int mi = 0; mi < 2; ++mi)
#pragma unroll
    for (int ni = 0; ni < 4; ++ni)
#pragma unroll
      for (int r = 0; r < 4; ++r)
        Oh[(rowbase + m0 + mi * 16 + lq * 4 + r) * 1024 + colbase + ni * 16 + lc] =
            f2bf(oacc[mi][ni][r]);
}

extern "C" void kernel_launch(void* const* d_in, const int* in_sizes, int n_in,
                              void* d_out, int out_size, void* d_ws, size_t ws_size,
                              hipStream_t stream) {
  (void)in_sizes; (void)n_in; (void)out_size; (void)ws_size;
  const float* q  = (const float*)d_in[0];
  const float* k  = (const float*)d_in[1];
  const float* v  = (const float*)d_in[2];
  const float* Wq = (const float*)d_in[3];
  const float* bq = (const float*)d_in[4];
  const float* Wk = (const float*)d_in[5];
  const float* bk = (const float*)d_in[6];
  const float* Wv = (const float*)d_in[7];
  const float* bv = (const float*)d_in[8];
  const float* Wo = (const float*)d_in[9];
  const float* bo = (const float*)d_in[10];

  uint8_t* ws = (uint8_t*)d_ws;
  const size_t WSZ = (size_t)1024 * 1024 * 2;   // 2 MB per transposed weight
  const size_t TSZ = (size_t)32768 * 1024 * 2;  // 64 MB per bf16 activation
  uint16_t* Wtq = (uint16_t*)(ws + 0 * WSZ);
  uint16_t* Wtk = (uint16_t*)(ws + 1 * WSZ);
  uint16_t* Wtv = (uint16_t*)(ws + 2 * WSZ);
  uint16_t* Wto = (uint16_t*)(ws + 3 * WSZ);
  uint16_t* Qh  = (uint16_t*)(ws + 4 * WSZ);
  uint16_t* Khp = (uint16_t*)(ws + 4 * WSZ + 1 * TSZ);
  uint16_t* Vhp = (uint16_t*)(ws + 4 * WSZ + 2 * TSZ);
  uint16_t* Xs  = (uint16_t*)(ws + 4 * WSZ + 3 * TSZ);  // staging / attn-out

  dim3 tb(256);
  wtrans<<<dim3(16, 16), tb, 0, stream>>>(Wq, Wtq);
  wtrans<<<dim3(16, 16), tb, 0, stream>>>(Wk, Wtk);
  wtrans<<<dim3(16, 16), tb, 0, stream>>>(Wv, Wtv);
  wtrans<<<dim3(16, 16), tb, 0, stream>>>(Wo, Wto);

  const long NE = (long)32768 * 1024;
  const dim3 gg(4, 128), gb(512);
  cvt_bf16<<<16384, tb, 0, stream>>>(q, Xs, NE);
  gemm256<<<gg, gb, 0, stream>>>(Xs, Wtq, bq, Qh, 0);
  cvt_bf16<<<16384, tb, 0, stream>>>(k, Xs, NE);
  gemm256<<<gg, gb, 0, stream>>>(Xs, Wtk, bk, Khp, 0);
  cvt_bf16<<<16384, tb, 0, stream>>>(v, Xs, NE);
  gemm256<<<gg, gb, 0, stream>>>(Xs, Wtv, bv, Vhp, 0);

  float* outp = (float*)d_out;
  attn<<<4096, tb, 0, stream>>>(Qh, Khp, Vhp, Xs, outp + (size_t)32768 * 1024);
  gemm256<<<gg, gb, 0, stream>>>(Xs, Wto, bo, outp, 1);
}